// Round 8
// baseline (306.559 us; speedup 1.0000x reference)
//
#include <hip/hip_runtime.h>
#include <hip/hip_bf16.h>
#include <math.h>

typedef __attribute__((ext_vector_type(8))) short bf16x8;
typedef __attribute__((ext_vector_type(4))) float f32x4;
typedef __attribute__((ext_vector_type(16))) float f32x16;
typedef __attribute__((ext_vector_type(4))) unsigned int u32x4;

#if __has_builtin(__builtin_amdgcn_exp2f)
#define EXP2(x) __builtin_amdgcn_exp2f(x)
#else
#define EXP2(x) __expf((x) * 0.6931471805599453f)
#endif

__device__ __forceinline__ ushort f2bf(float f) {
  unsigned u = __float_as_uint(f);
  u = u + 0x7FFFu + ((u >> 16) & 1u);
  return (ushort)(u >> 16);
}
__device__ __forceinline__ float bf2f(ushort h) {
  return __uint_as_float(((unsigned)h) << 16);
}
// single-instruction packed f32->bf16 pair (RNE, same as manual round)
__device__ __forceinline__ unsigned cvtpk(float a, float b) {
  unsigned r;
  asm("v_cvt_pk_bf16_f32 %0, %1, %2" : "=v"(r) : "v"(a), "v"(b));
  return r;
}
__device__ __forceinline__ void gload_lds16(const ushort* g, ushort* l) {
  __builtin_amdgcn_global_load_lds((const __attribute__((address_space(1))) void*)g,
                                   (__attribute__((address_space(3))) void*)l, 16, 0, 0);
}

// ---------------------------------------------------------------- prep: casts + packing + rope table
__global__ __launch_bounds__(256) void prep_kernel(
    const float* __restrict__ hs, const float* __restrict__ qw,
    const float* __restrict__ kw, const float* __restrict__ vw,
    const float* __restrict__ ow, const float* __restrict__ qb,
    const float* __restrict__ kb, const float* __restrict__ vb,
    ushort* __restrict__ hs_b, ushort* __restrict__ qkvw_b,
    ushort* __restrict__ ow_b, float* __restrict__ qkvb,
    float2* __restrict__ rope_tab)
{
  const int idx = blockIdx.x * 256 + threadIdx.x;
  const int stride = gridDim.x * 256;
  const float4* hs4 = (const float4*)hs;
  const float4* qw4 = (const float4*)qw;
  const float4* kw4 = (const float4*)kw;
  const float4* vw4 = (const float4*)vw;
  const float4* ow4 = (const float4*)ow;
  ushort4* hsb4 = (ushort4*)hs_b;
  ushort4* qkvwb4 = (ushort4*)qkvw_b;
  ushort4* owb4 = (ushort4*)ow_b;

  for (int i = idx; i < 2097152; i += stride) {
    float4 v = hs4[i];
    ushort4 o; o.x=f2bf(v.x); o.y=f2bf(v.y); o.z=f2bf(v.z); o.w=f2bf(v.w);
    hsb4[i] = o;
  }
  for (int i = idx; i < 1048576; i += stride) {
    float4 v = qw4[i];
    ushort4 o; o.x=f2bf(v.x); o.y=f2bf(v.y); o.z=f2bf(v.z); o.w=f2bf(v.w);
    qkvwb4[i] = o;
  }
  for (int i = idx; i < 262144; i += stride) {
    float4 v = kw4[i];
    ushort4 o; o.x=f2bf(v.x); o.y=f2bf(v.y); o.z=f2bf(v.z); o.w=f2bf(v.w);
    qkvwb4[1048576 + i] = o;
  }
  for (int i = idx; i < 262144; i += stride) {
    float4 v = vw4[i];
    ushort4 o; o.x=f2bf(v.x); o.y=f2bf(v.y); o.z=f2bf(v.z); o.w=f2bf(v.w);
    qkvwb4[1310720 + i] = o;
  }
  for (int i = idx; i < 1048576; i += stride) {
    float4 v = ow4[i];
    ushort4 o; o.x=f2bf(v.x); o.y=f2bf(v.y); o.z=f2bf(v.z); o.w=f2bf(v.w);
    owb4[i] = o;
  }
  for (int i = idx; i < 3072; i += stride)
    qkvb[i] = (i < 2048) ? qb[i] : (i < 2560 ? kb[i - 2048] : vb[i - 2560]);
  // rope cos/sin table: [pos 0..2047][pair 0..63]
  for (int i = idx; i < 131072; i += stride) {
    int pos = i >> 6, d = i & 63;
    float inv = __expf((float)d * -0.14391156831212787f);
    float ang = (float)pos * inv;
    rope_tab[i] = make_float2(cosf(ang), sinf(ang));
  }
}

// ---------------------------------------------------------------- 128x128 GEMM, 2 waves of 64x128
// R7 geometry (12 ds_read_b128 / 32 MFMA per wave-tile) + 3-SLOT / 2-TILES-AHEAD
// pipeline: prologue stages tiles 0,1; tile t p0 issues A(t+2) -> slot (t+2)%3 then
// gates vmcnt(12) (newest 12 = t+1's 8 + t+2's A-4 stay in flight; exactly tile t's
// 8 drain); p1 issues B(t+2). Issue->consume distance = a full tile (>=500 cyc) —
// covers L2-hit latency (~200-225 cyc) that the 2-slot gate (one phase, ~130 cyc)
// could not. Slot-reuse safe: A(t+2) targets slot (t-1)%3; all reads of it finished
// before the end-of-tile-(t-1) barrier that precedes this issue in program order.
// Epilogue gates: vmcnt(8) at t=nt-2, vmcnt(0) at t=nt-1. LDS 48 KB is free:
// occupancy is grid-limited (3 blocks/CU qkv, 2 O-proj). asm fences per rule #18.
// MODE 1: QKV + fused rope (pair (d,d+64) = (ni,ni+4), in-lane) + V^T store.
// MODE 0: f32 out, ldc=2048.
template<int MODE>
__global__ __launch_bounds__(128, 2) void gemm128(
    const ushort* __restrict__ A, const ushort* __restrict__ Bw,
    const float* __restrict__ bias, void* __restrict__ out,
    ushort* __restrict__ vt, const float2* __restrict__ tab)
{
  __shared__ ushort smem[3][8192];  // slot: A[128][32] @0, B[128][32] @4096
  const int tid = threadIdx.x;               // 0..127
  const int lane = tid & 63, wv = tid >> 6;  // 2 waves
  const int qd = lane >> 4, ln = lane & 15;
  const long row0 = (long)blockIdx.x * 128, col0 = (long)blockIdx.y * 128;

  f32x4 acc[4][8];   // mi: 4 row-frags (64 rows of this wave), ni: 8 col-frags
#pragma unroll
  for (int i = 0; i < 4; i++)
#pragma unroll
    for (int j = 0; j < 8; j++) acc[i][j] = (f32x4){0.f, 0.f, 0.f, 0.f};

  const ushort* gA = A + (row0 + (tid >> 2)) * 2048l + (tid & 3) * 8;
  const ushort* gB = Bw + (col0 + (tid >> 2)) * 2048l + (tid & 3) * 8;
  const long R32 = 32l * 2048;     // +32 rows
  const int tid8 = tid * 8;        // = row*32 + chunk*8 within a 32-row band

  // prologue: stage tile 0 -> slot 0, tile 1 -> slot 1
#pragma unroll
  for (int i = 0; i < 4; i++) gload_lds16(gA + i * R32,      &smem[0][i * 1024 + tid8]);
#pragma unroll
  for (int i = 0; i < 4; i++) gload_lds16(gB + i * R32,      &smem[0][4096 + i * 1024 + tid8]);
#pragma unroll
  for (int i = 0; i < 4; i++) gload_lds16(gA + 32 + i * R32, &smem[1][i * 1024 + tid8]);
#pragma unroll
  for (int i = 0; i < 4; i++) gload_lds16(gB + 32 + i * R32, &smem[1][4096 + i * 1024 + tid8]);

  int st = 0;  // slot of the tile being consumed (t % 3)
  for (int kt = 0; kt < 2048; kt += 32) {
    const int ds = (st >= 1) ? st - 1 : 2;   // (st + 2) % 3 — destination slot for tile t+2
    const ushort* As = smem[st];
    const ushort* Bs = As + 4096;
    ushort* Dst = smem[ds];

    // ---- phase 0: issue A(t+2), counted gate, rows wv*64+0..31 ----
    if (kt < 1984) {                          // t+2 exists
#pragma unroll
      for (int i = 0; i < 4; i++)
        gload_lds16(gA + kt + 64 + i * R32, Dst + i * 1024 + tid8);
      asm volatile("s_waitcnt vmcnt(12)" ::: "memory");  // drain exactly tile t's 8
    } else if (kt < 2016) {                   // t = nt-2: only tile nt-1's 8 in flight
      asm volatile("s_waitcnt vmcnt(8)" ::: "memory");
    } else {                                  // t = nt-1
      asm volatile("s_waitcnt vmcnt(0)" ::: "memory");
    }
    __builtin_amdgcn_s_barrier();
    asm volatile("" ::: "memory");
    bf16x8 bf[8], af[2];
#pragma unroll
    for (int ni = 0; ni < 8; ni++)
      bf[ni] = *(const bf16x8*)&Bs[(ni * 16 + ln) * 32 + qd * 8];
#pragma unroll
    for (int mi = 0; mi < 2; mi++)
      af[mi] = *(const bf16x8*)&As[(wv * 64 + mi * 16 + ln) * 32 + qd * 8];
    __builtin_amdgcn_s_setprio(1);
#pragma unroll
    for (int mi = 0; mi < 2; mi++)
#pragma unroll
      for (int ni = 0; ni < 8; ni++)
        acc[mi][ni] = __builtin_amdgcn_mfma_f32_16x16x32_bf16(af[mi], bf[ni], acc[mi][ni], 0, 0, 0);
    __builtin_amdgcn_s_setprio(0);

    // ---- phase 1: rows wv*64+32..63, issue B(t+2) ----
    bf16x8 ag[2];
#pragma unroll
    for (int mi = 0; mi < 2; mi++)
      ag[mi] = *(const bf16x8*)&As[(wv * 64 + 32 + mi * 16 + ln) * 32 + qd * 8];
    if (kt < 1984) {
#pragma unroll
      for (int i = 0; i < 4; i++)
        gload_lds16(gB + kt + 64 + i * R32, Dst + 4096 + i * 1024 + tid8);
    }
    __builtin_amdgcn_s_setprio(1);
#pragma unroll
    for (int mi = 0; mi < 2; mi++)
#pragma unroll
      for (int ni = 0; ni < 8; ni++)
        acc[mi + 2][ni] = __builtin_amdgcn_mfma_f32_16x16x32_bf16(ag[mi], bf[ni], acc[mi + 2][ni], 0, 0, 0);
    __builtin_amdgcn_s_setprio(0);
    asm volatile("" ::: "memory");   // pin ds_reads above the barrier
    __builtin_amdgcn_s_barrier();
    asm volatile("" ::: "memory");

    st = (st == 2) ? 0 : st + 1;
  }

  float bv[8];
#pragma unroll
  for (int ni = 0; ni < 8; ni++) bv[ni] = bias[col0 + ni * 16 + ln];

  if (MODE == 0) {
    float* C = (float*)out;
#pragma unroll
    for (int mi = 0; mi < 4; mi++)
#pragma unroll
      for (int ni = 0; ni < 8; ni++)
#pragma unroll
        for (int r = 0; r < 4; r++) {
          long row = row0 + wv * 64 + mi * 16 + qd * 4 + r;
          long col = col0 + ni * 16 + ln;
          C[row * 2048 + col] = acc[mi][ni][r] + bv[ni];
        }
  } else if (col0 >= 2560) {
    // V: transposed store into vt [512][4096]
#pragma unroll
    for (int mi = 0; mi < 4; mi++)
#pragma unroll
      for (int ni = 0; ni < 8; ni++)
#pragma unroll
        for (int r = 0; r < 4; r++) {
          long row = row0 + wv * 64 + mi * 16 + qd * 4 + r;
          long col = col0 + ni * 16 + ln - 2560;
          vt[col * 4096 + row] = f2bf(acc[mi][ni][r] + bv[ni]);
        }
  } else {
    // Q or K: fused rope (R2-verified): pair (d, d+64) = (ni, ni+4), in-lane.
    ushort* qkbuf = (ushort*)out;
    const float sc = (col0 < 2048) ? 0.12751744399764505f : 1.0f;  // log2(e)/sqrt(128)
#pragma unroll
    for (int mi = 0; mi < 4; mi++)
#pragma unroll
      for (int ni = 0; ni < 4; ni++) {
        const int d = ni * 16 + ln;           // 0..63
#pragma unroll
        for (int r = 0; r < 4; r++) {
          long row = row0 + wv * 64 + mi * 16 + qd * 4 + r;
          int pos = (int)(row & 2047);
          float2 cs = tab[pos * 64 + d];
          float c = cs.x * sc, s = cs.y * sc;
          float v0 = acc[mi][ni][r]     + bv[ni];
          float v1 = acc[mi][ni + 4][r] + bv[ni + 4];
          ushort* p = qkbuf + row * 2560 + col0 + d;
          p[0]  = f2bf(v0 * c - v1 * s);
          p[64] = f2bf(v1 * c + v0 * s);
        }
      }
  }
}

// ---------------------------------------------------------------- flash attention v7 (proven: 82 µs)
// T12 softmax (exp2 with log2e folded in rope scale, v_cvt_pk_bf16_f32, permlane32_swap),
// T5 setprio around MFMA clusters, DMA double-buffer, XOR-chunk swizzle on global side.
// LDS-staged V (v8's V-in-reg spilled: 128-VGPR cap at occ 4 vs ~180 needed).
__global__ __launch_bounds__(256, 2) void flash_kernel(
    const ushort* __restrict__ qk, const ushort* __restrict__ vt,
    ushort* __restrict__ ctx)
{
  __shared__ ushort smem[32768];  // buf0: Ks[64][128]@0, Vts[128][64]@8192; buf1 @16384
  const int t = threadIdx.x, lane = t & 63, wv = t >> 6;
  const int h2 = lane >> 5, m = lane & 31;
  const int q0 = blockIdx.x * 128;
  const int b = blockIdx.y >> 4, h = blockIdx.y & 15;
  const long rb = (long)b * 2048;
  const ushort* Qg  = qk + (rb + q0) * 2560 + h * 128;
  const ushort* Kg  = qk + rb * 2560 + 2048 + (h >> 2) * 128;
  const ushort* Vtg = vt + ((long)(h >> 2) * 128) * 4096 + rb;

  // Q B-frags in registers: lane (h2, m) holds Q[q = wv*32+m][d = 16*s2 + 8*h2 + 0..7]
  bf16x8 qf[8];
  {
    const ushort* qrow = Qg + (long)(wv * 32 + m) * 2560 + h2 * 8;
#pragma unroll
    for (int s2 = 0; s2 < 8; s2++)
      qf[s2] = *(const bf16x8*)(qrow + s2 * 16);
  }

  f32x16 oacc[4];
#pragma unroll
  for (int d = 0; d < 4; d++)
#pragma unroll
    for (int r = 0; r < 16; r++) oacc[d][r] = 0.f;
  float l_run = 0.f;

  // per-lane global staging addresses (tile 0), swizzled chunk on global side
  const ushort* gK[4];
  const ushort* gV[4];
#pragma unroll
  for (int s = 0; s < 4; s++) {
    int krow = wv * 16 + s * 4 + (lane >> 4);              // 0..63
    int kcd  = (lane & 15) ^ (krow & 15);
    gK[s] = Kg + (long)krow * 2560 + kcd * 8;
    int vrow = wv * 32 + s * 8 + (lane >> 3);              // 0..127
    int vcd  = (lane & 7) ^ ((lane >> 3) & 7);
    gV[s] = Vtg + (long)vrow * 4096 + vcd * 8;
  }
  const int ldsK = wv * 16 * 128;                          // + s*4*128
  const int ldsV = 8192 + wv * 32 * 64;                    // + s*8*64

  // preload tile 0 -> buf 0, advance pointers to tile 1
#pragma unroll
  for (int s = 0; s < 4; s++) gload_lds16(gK[s], smem + ldsK + s * 512);
#pragma unroll
  for (int s = 0; s < 4; s++) gload_lds16(gV[s], smem + ldsV + s * 512);
#pragma unroll
  for (int s = 0; s < 4; s++) { gK[s] += 64l * 2560; gV[s] += 64; }

  const int mk = (m & 15);    // K swizzle key
  const int mv = (m & 7);     // V swizzle key

  for (int kt = 0; kt < 2048; kt += 64) {
    const int cb = (kt >> 6) & 1;
    __syncthreads();   // drains DMA for this tile; prev tile's LDS reads done
    if (kt < 1984) {   // issue tile i+1 into the other buffer (in flight across compute)
      ushort* nb = smem + (cb ^ 1) * 16384;
#pragma unroll
      for (int s = 0; s < 4; s++) gload_lds16(gK[s], nb + ldsK + s * 512);
#pragma unroll
      for (int s = 0; s < 4; s++) gload_lds16(gV[s], nb + ldsV + s * 512);
#pragma unroll
      for (int s = 0; s < 4; s++) { gK[s] += 64l * 2560; gV[s] += 64; }
    }
    const ushort* KsB  = smem + cb * 16384;
    const ushort* VtsB = KsB + 8192;

    float s_sum = 0.f;
#pragma unroll
    for (int kb = 0; kb < 2; kb++) {
      f32x16 sacc;
#pragma unroll
      for (int r = 0; r < 16; r++) sacc[r] = 0.f;
      __builtin_amdgcn_s_setprio(1);
#pragma unroll
      for (int s2 = 0; s2 < 8; s2++) {
        bf16x8 kf = *(const bf16x8*)&KsB[(32 * kb + m) * 128 + ((s2 * 2 + h2) ^ mk) * 8];
        sacc = __builtin_amdgcn_mfma_f32_32x32x16_bf16(kf, qf[s2], sacc, 0, 0, 0);
      }
      __builtin_amdgcn_s_setprio(0);
#pragma unroll
      for (int sh = 0; sh < 2; sh++) {
        float e0 = EXP2(sacc[8 * sh + 0]);
        float e1 = EXP2(sacc[8 * sh + 1]);
        float e2 = EXP2(sacc[8 * sh + 2]);
        float e3 = EXP2(sacc[8 * sh + 3]);
        float e4 = EXP2(sacc[8 * sh + 4]);
        float e5 = EXP2(sacc[8 * sh + 5]);
        float e6 = EXP2(sacc[8 * sh + 6]);
        float e7 = EXP2(sacc[8 * sh + 7]);
        s_sum += ((e0 + e1) + (e2 + e3)) + ((e4 + e5) + (e6 + e7));
        unsigned u0 = cvtpk(e0, e1);
        unsigned u1 = cvtpk(e2, e3);
        unsigned u2 = cvtpk(e4, e5);
        unsigned u3 = cvtpk(e6, e7);
        auto r0 = __builtin_amdgcn_permlane32_swap(u0, u2, false, false);
        auto r1 = __builtin_amdgcn_permlane32_swap(u1, u3, false, false);
        u32x4 pu;
        pu.x = r0[0];
        pu.y = r1[0];
        pu.z = r0[1];
        pu.w = r1[1];
        bf16x8 pfv = __builtin_bit_cast(bf16x8, pu);
        const int s = 2 * kb + sh;
        __builtin_amdgcn_s_setprio(1);
#pragma unroll
        for (int db = 0; db < 4; db++) {
          bf16x8 vf = *(const bf16x8*)&VtsB[(db * 32 + m) * 64 + ((s * 2 + h2) ^ mv) * 8];
          oacc[db] = __builtin_amdgcn_mfma_f32_32x32x16_bf16(vf, pfv, oacc[db], 0, 0, 0);
        }
        __builtin_amdgcn_s_setprio(0);
      }
    }
    l_run += s_sum + __int_as_float(__shfl_xor(__float_as_int(s_sum), 32, 64));
  }

  // epilogue: O^T/l -> LDS transpose -> coalesced ctx stores
  const float linv = 1.f / (l_run + 1e-10f);
  __syncthreads();                          // all waves done with staging buffers
  ushort* Obuf = smem;                      // [128 q][136]
#pragma unroll
  for (int db = 0; db < 4; db++)
#pragma unroll
    for (int r = 0; r < 16; r++) {
      int d = db * 32 + (r & 3) + 8 * (r >> 2) + 4 * h2;
      Obuf[(wv * 32 + m) * 136 + d] = f2bf(oacc[db][r] * linv);
    }
  __syncthreads();
  {
    int qr = t >> 1;
    ushort* dst = ctx + (rb + q0 + qr) * 2048 + h * 128;
#pragma unroll
    for (int c = 0; c < 8; c++) {
      int off = ((t & 1) * 8 + c) * 8;
      *(uint4*)(dst + off) = *(const uint4*)&Obuf[qr * 136 + off];
    }
  }
}

// ---------------------------------------------------------------- launch
extern "C" void kernel_launch(void* const* d_in, const int* in_sizes, int n_in,
                              void* d_out, int out_size, void* d_ws, size_t ws_size,
                              hipStream_t stream)
{
  const float* hs = (const float*)d_in[0];
  const float* qw = (const float*)d_in[1];
  const float* qb = (const float*)d_in[2];
  const float* kw = (const float*)d_in[3];
  const float* kb = (const float*)d_in[4];
  const float* vw = (const float*)d_in[5];
  const float* vb = (const float*)d_in[6];
  const float* ow = (const float*)d_in[7];
  const float* ob = (const float*)d_in[8];

  char* ws = (char*)d_ws;
  ushort* hs_b   = (ushort*)(ws);                 // 16,777,216 B
  ushort* qkvw_b = (ushort*)(ws + 16777216);      // 12,582,912 B
  ushort* ow_b   = (ushort*)(ws + 29360128);      //  8,388,608 B
  float*  qkvb   = (float*) (ws + 37748736);      //     12,288 B
  ushort* qkbuf  = (ushort*)(ws + 37761024);      // 20,971,520 B  [4096][2560]
  ushort* vtbuf  = (ushort*)(ws + 58732544);      //  4,194,304 B  [512][4096]
  ushort* ctx    = (ushort*)(ws + 62926848);      // 16,777,216 B
  // rope table lives at the head of ctx: only needed until gemm_qkv completes;
  // flash overwrites ctx afterwards (stream-ordered, safe). 2048*64*8 B = 1 MB.
  float2* rope_tab = (float2*)(ws + 62926848);

  prep_kernel<<<1024, 256, 0, stream>>>(hs, qw, kw, vw, ow, qb, kb, vb,
                                        hs_b, qkvw_b, ow_b, qkvb, rope_tab);
  gemm128<1><<<dim3(32, 24), 128, 0, stream>>>(hs_b, qkvw_b, qkvb, (void*)qkbuf,
                                               vtbuf, rope_tab);
  flash_kernel<<<dim3(16, 32), 256, 0, stream>>>(qkbuf, vtbuf, ctx);
  gemm128<0><<<dim3(32, 16), 128, 0, stream>>>(ctx, ow_b, ob, d_out,
                                               nullptr, nullptr);
}